// Round 1
// baseline (5999.292 us; speedup 1.0000x reference)
//
#include <hip/hip_runtime.h>
#include <hip/hip_bf16.h>

#define N_NODES 50000
#define N_EDGES 800000
#define DXF 28
#define EDIM 26
#define G_GRAPHS 64

typedef __hip_bfloat16 bf16;

__device__ __forceinline__ float leakyf(float x){ return x >= 0.f ? x : 0.01f*x; }

// ---------------------------------------------------------------------------
// Embed: s[n, 0:128] = MLP(concat(x, fs, fn)), s[n, 128:256] = action_x @ aw + ab
// 16 nodes per block, 256 threads (thread = output column).
// ---------------------------------------------------------------------------
__global__ __launch_bounds__(256) void embed_kernel(
    const float* __restrict__ x, const float* __restrict__ fs,
    const float* __restrict__ fn, const float* __restrict__ act,
    const float* __restrict__ ew1, const float* __restrict__ eb1,
    const float* __restrict__ ew2, const float* __restrict__ eb2,
    const float* __restrict__ ew3, const float* __restrict__ eb3,
    const float* __restrict__ aw,  const float* __restrict__ ab,
    float* __restrict__ s_out)
{
  __shared__ float in_s[16][32];
  __shared__ float h_a[16][256];
  __shared__ float h_b[16][256];
  const int t = threadIdx.x;
  const int node0 = blockIdx.x * 16;

  for (int idx = t; idx < 16*32; idx += 256) {
    int n = idx >> 5, k = idx & 31;
    int node = node0 + n;
    float v;
    if (k < DXF)      v = x[node*DXF + k];
    else if (k < 31)  v = fs[node*3 + (k - DXF)];
    else              v = fn[node];
    in_s[n][k] = v;
  }
  __syncthreads();

  // stage 1: 32 -> 256
  {
    float acc[16];
    float bb = eb1[t];
    #pragma unroll
    for (int n=0;n<16;n++) acc[n] = bb;
    for (int k=0;k<32;k++){
      float w = ew1[k*256 + t];
      #pragma unroll
      for (int n=0;n<16;n++) acc[n] = fmaf(in_s[n][k], w, acc[n]);
    }
    #pragma unroll
    for (int n=0;n<16;n++) h_a[n][t] = leakyf(acc[n]);
  }
  __syncthreads();

  // load action tile into in_s (no longer needed) while stage 2 runs
  if (t < 48){
    int n = t / 3, k = t % 3;
    in_s[n][k] = act[(node0+n)*3 + k];
  }

  // stage 2: 256 -> 256
  {
    float acc[16];
    float bb = eb2[t];
    #pragma unroll
    for (int n=0;n<16;n++) acc[n] = bb;
    for (int k4=0;k4<256;k4+=4){
      float w0 = ew2[(k4+0)*256 + t];
      float w1 = ew2[(k4+1)*256 + t];
      float w2 = ew2[(k4+2)*256 + t];
      float w3 = ew2[(k4+3)*256 + t];
      #pragma unroll
      for (int n=0;n<16;n++){
        const float4 sv = *reinterpret_cast<const float4*>(&h_a[n][k4]);
        acc[n] = fmaf(sv.x,w0,fmaf(sv.y,w1,fmaf(sv.z,w2,fmaf(sv.w,w3,acc[n]))));
      }
    }
    #pragma unroll
    for (int n=0;n<16;n++) h_b[n][t] = leakyf(acc[n]);
  }
  __syncthreads();

  // stage 3: threads 0..127 -> h3 column t; threads 128..255 -> action column t-128
  if (t < 128){
    float acc[16];
    float bb = eb3[t];
    #pragma unroll
    for (int n=0;n<16;n++) acc[n] = bb;
    for (int k4=0;k4<256;k4+=4){
      float w0 = ew3[(k4+0)*128 + t];
      float w1 = ew3[(k4+1)*128 + t];
      float w2 = ew3[(k4+2)*128 + t];
      float w3 = ew3[(k4+3)*128 + t];
      #pragma unroll
      for (int n=0;n<16;n++){
        const float4 sv = *reinterpret_cast<const float4*>(&h_b[n][k4]);
        acc[n] = fmaf(sv.x,w0,fmaf(sv.y,w1,fmaf(sv.z,w2,fmaf(sv.w,w3,acc[n]))));
      }
    }
    #pragma unroll
    for (int n=0;n<16;n++) s_out[(size_t)(node0+n)*256 + t] = leakyf(acc[n]);
  } else {
    int c = t - 128;
    float w0 = aw[0*128 + c], w1 = aw[1*128 + c], w2 = aw[2*128 + c];
    float bb = ab[c];
    #pragma unroll
    for (int n=0;n<16;n++){
      float v = bb + in_s[n][0]*w0 + in_s[n][1]*w1 + in_s[n][2]*w2;
      s_out[(size_t)(node0+n)*256 + 128 + c] = v;
    }
  }
}

// ---------------------------------------------------------------------------
// Proj: P[n] = [ s@Wf[0:256] | s@Ws[0:256] | s@Wf[256:512] | s@Ws[256:512] ]
// bf16 output, 32 nodes per block.
// ---------------------------------------------------------------------------
__global__ __launch_bounds__(256) void proj_kernel(
    const float* __restrict__ s_in,
    const float* __restrict__ wf,   // layer base [538][256]
    const float* __restrict__ wsm,  // layer base [538][256]
    bf16* __restrict__ P)
{
  __shared__ float sN[32][256];
  const int t = threadIdx.x;
  const int node0 = blockIdx.x * 32;

  for (int n=0;n<32;n++){
    int node = node0 + n;
    sN[n][t] = (node < N_NODES) ? s_in[(size_t)node*256 + t] : 0.f;
  }
  __syncthreads();

  const float* Wc[4] = { wf, wsm, wf + 256*256, wsm + 256*256 };
  for (int chunk=0; chunk<4; chunk++){
    const float* W = Wc[chunk];
    float acc[32];
    #pragma unroll
    for (int n=0;n<32;n++) acc[n] = 0.f;
    for (int k4=0;k4<256;k4+=4){
      float w0 = W[(k4+0)*256 + t];
      float w1 = W[(k4+1)*256 + t];
      float w2 = W[(k4+2)*256 + t];
      float w3 = W[(k4+3)*256 + t];
      #pragma unroll
      for (int n=0;n<32;n++){
        const float4 sv = *reinterpret_cast<const float4*>(&sN[n][k4]);
        acc[n] = fmaf(sv.x,w0,fmaf(sv.y,w1,fmaf(sv.z,w2,fmaf(sv.w,w3,acc[n]))));
      }
    }
    for (int n=0;n<32;n++){
      int node = node0 + n;
      if (node < N_NODES)
        P[(size_t)node*1024 + chunk*256 + t] = __float2bfloat16(acc[n]);
    }
  }
}

// ---------------------------------------------------------------------------
// Edge: per edge, gate/core logits = P gathers + gauss(26) @ We + b, then
// m = sigmoid(gf)*softplus(gs); atomicAdd into s (residual + segment_sum).
// ---------------------------------------------------------------------------
__global__ __launch_bounds__(256) void edge_kernel(
    const bf16* __restrict__ P,
    const float* __restrict__ wfe,  // [26][256]
    const float* __restrict__ wse,  // [26][256]
    const float* __restrict__ bfv, const float* __restrict__ bsv,
    const int* __restrict__ ei,     // [2][E]
    const float* __restrict__ elen,
    float* __restrict__ s_buf)
{
  __shared__ float wfeS[EDIM*256];
  __shared__ float wseS[EDIM*256];
  __shared__ float gaussS[64*EDIM];
  __shared__ int srcS[64];
  __shared__ int dstS[64];
  const int t = threadIdx.x;

  for (int i=t; i<EDIM*256; i+=256){ wfeS[i]=wfe[i]; wseS[i]=wse[i]; }
  const float bf_t = bfv[t], bs_t = bsv[t];

  const int ntiles = N_EDGES/64;
  for (int tile = blockIdx.x; tile < ntiles; tile += gridDim.x){
    const int e0 = tile*64;
    __syncthreads();   // staging / previous-iteration reads complete
    if (t < 64){ srcS[t] = ei[e0+t]; dstS[t] = ei[N_EDGES + e0+t]; }
    for (int it=t; it<64*EDIM; it+=256){
      int el = it/EDIM, k = it - el*EDIM;
      float d = elen[e0+el] - 0.2f*(float)k;
      gaussS[el*EDIM+k] = __expf(-25.f*d*d);
    }
    __syncthreads();
    for (int el=0; el<64; el++){
      const int sn = srcS[el], dn = dstS[el];
      const size_t pd = (size_t)dn*1024, ps = (size_t)sn*1024;
      float gf = bf_t + __bfloat162float(P[pd + t])       + __bfloat162float(P[ps + 512 + t]);
      float gs = bs_t + __bfloat162float(P[pd + 256 + t]) + __bfloat162float(P[ps + 768 + t]);
      const float* gp = &gaussS[el*EDIM];
      #pragma unroll
      for (int k=0;k<EDIM;k++){
        float g = gp[k];
        gf = fmaf(g, wfeS[k*256+t], gf);
        gs = fmaf(g, wseS[k*256+t], gs);
      }
      float gate = 1.f / (1.f + __expf(-gf));
      float core = fmaxf(gs, 0.f) + log1pf(__expf(-fabsf(gs)));
      atomicAdd(&s_buf[(size_t)dn*256 + t], gate*core);
    }
  }
}

__global__ __launch_bounds__(256) void leaky_kernel(float* __restrict__ s_buf)
{
  const size_t total = (size_t)N_NODES*256/4;
  float4* p = (float4*)s_buf;
  for (size_t i = (size_t)blockIdx.x*blockDim.x + threadIdx.x; i < total;
       i += (size_t)gridDim.x*blockDim.x){
    float4 v = p[i];
    v.x = leakyf(v.x); v.y = leakyf(v.y); v.z = leakyf(v.z); v.w = leakyf(v.w);
    p[i] = v;
  }
}

// ---------------------------------------------------------------------------
// Pool: batch is sorted; each block reduces 64 contiguous nodes with
// register accumulation per graph segment, then atomicAdd.
// ---------------------------------------------------------------------------
__global__ __launch_bounds__(256) void pool_kernel(
    const float* __restrict__ s_buf, const int* __restrict__ batch,
    float* __restrict__ y)
{
  const int t = threadIdx.x;
  int n0 = blockIdx.x * 64;
  int nend = min(n0 + 64, N_NODES);
  float acc = 0.f;
  int cur = -1;
  for (int n=n0; n<nend; n++){
    int g = batch[n];
    if (g != cur){
      if (cur >= 0) atomicAdd(&y[cur*256 + t], acc);
      acc = 0.f; cur = g;
    }
    acc += s_buf[(size_t)n*256 + t];
  }
  if (cur >= 0) atomicAdd(&y[cur*256 + t], acc);
}

__global__ __launch_bounds__(256) void desc_kernel(
    const float* __restrict__ y,
    const float* __restrict__ w1, const float* __restrict__ b1,
    const float* __restrict__ w2, const float* __restrict__ b2,
    float* __restrict__ out)
{
  __shared__ float yS[256];
  __shared__ float red[256];
  const int g = blockIdx.x, t = threadIdx.x;
  yS[t] = y[g*256 + t];
  __syncthreads();
  float acc = b1[t];
  for (int k4=0;k4<256;k4+=4){
    float4 v = *reinterpret_cast<const float4*>(&yS[k4]);
    acc += v.x*w1[(k4+0)*256+t] + v.y*w1[(k4+1)*256+t]
         + v.z*w1[(k4+2)*256+t] + v.w*w1[(k4+3)*256+t];
  }
  red[t] = fmaxf(acc, 0.f) * w2[t];
  __syncthreads();
  for (int off=128; off>0; off>>=1){
    if (t < off) red[t] += red[t+off];
    __syncthreads();
  }
  if (t == 0) out[g] = red[0] + b2[0];
}

// ---------------------------------------------------------------------------
extern "C" void kernel_launch(void* const* d_in, const int* in_sizes, int n_in,
                              void* d_out, int out_size, void* d_ws, size_t ws_size,
                              hipStream_t stream)
{
  const float* x    = (const float*)d_in[0];
  const float* fs   = (const float*)d_in[1];
  const float* fn   = (const float*)d_in[2];
  const float* act  = (const float*)d_in[3];
  const float* elen = (const float*)d_in[4];
  const float* ew1  = (const float*)d_in[5];
  const float* eb1  = (const float*)d_in[6];
  const float* ew2  = (const float*)d_in[7];
  const float* eb2  = (const float*)d_in[8];
  const float* ew3  = (const float*)d_in[9];
  const float* eb3  = (const float*)d_in[10];
  const float* aw   = (const float*)d_in[11];
  const float* ab   = (const float*)d_in[12];
  const float* cwf  = (const float*)d_in[13];
  const float* cbf  = (const float*)d_in[14];
  const float* cws  = (const float*)d_in[15];
  const float* cbs  = (const float*)d_in[16];
  const float* dw1  = (const float*)d_in[17];
  const float* db1  = (const float*)d_in[18];
  const float* dw2  = (const float*)d_in[19];
  const float* db2  = (const float*)d_in[20];
  const int*   ei   = (const int*)d_in[21];
  const int*   batch= (const int*)d_in[22];
  float* out = (float*)d_out;

  const size_t s_bytes = (size_t)N_NODES*256*sizeof(float);   // 51.2 MB
  const size_t p_bytes = (size_t)N_NODES*1024*sizeof(bf16);   // 102.4 MB
  const size_t y_bytes = (size_t)G_GRAPHS*256*sizeof(float);  // 64 KB
  if (ws_size < s_bytes + p_bytes + y_bytes) return;

  char* ws = (char*)d_ws;
  float* s_buf = (float*)ws;
  bf16*  P     = (bf16*)(ws + s_bytes);
  float* y     = (float*)(ws + s_bytes + p_bytes);

  hipMemsetAsync(y, 0, y_bytes, stream);
  embed_kernel<<<N_NODES/16, 256, 0, stream>>>(x, fs, fn, act,
      ew1, eb1, ew2, eb2, ew3, eb3, aw, ab, s_buf);

  for (int l=0; l<3; l++){
    const float* wf  = cwf + (size_t)l*538*256;
    const float* wsm = cws + (size_t)l*538*256;
    proj_kernel<<<(N_NODES+31)/32, 256, 0, stream>>>(s_buf, wf, wsm, P);
    edge_kernel<<<2048, 256, 0, stream>>>(P, wf + 512*256, wsm + 512*256,
        cbf + l*256, cbs + l*256, ei, elen, s_buf);
    if (l < 2) leaky_kernel<<<2048, 256, 0, stream>>>(s_buf);
  }

  pool_kernel<<<(N_NODES+63)/64, 256, 0, stream>>>(s_buf, batch, y);
  desc_kernel<<<G_GRAPHS, 256, 0, stream>>>(y, dw1, db1, dw2, db2, out);
}

// Round 2
// 1887.488 us; speedup vs baseline: 3.1785x; 3.1785x over previous
//
#include <hip/hip_runtime.h>
#include <hip/hip_bf16.h>

#define N_NODES 50000
#define NPAD    50048
#define N_EDGES 800000
#define EDIM 26
#define DXF 28
#define G_GRAPHS 64

typedef __attribute__((ext_vector_type(8))) short short8v;
typedef __attribute__((ext_vector_type(4))) float f32x4;
typedef unsigned short u16;
typedef unsigned int u32;

__device__ __forceinline__ float leakyf(float x){ return x >= 0.f ? x : 0.01f*x; }
__device__ __forceinline__ u16 f2bf(float f){
  __hip_bfloat16 h = __float2bfloat16(f);
  return __builtin_bit_cast(u16, h);
}
__device__ __forceinline__ float bf2f(u16 u){
  return __builtin_bit_cast(float, (u32)u << 16);
}

// ---------------------------------------------------------------------------
// Embed: sB[n, 0:128] = MLP(concat(x, fs, fn)), sB[n, 128:256] = action @ aw + ab
// ---------------------------------------------------------------------------
__global__ __launch_bounds__(256) void embed_kernel(
    const float* __restrict__ x, const float* __restrict__ fs,
    const float* __restrict__ fn, const float* __restrict__ act,
    const float* __restrict__ ew1, const float* __restrict__ eb1,
    const float* __restrict__ ew2, const float* __restrict__ eb2,
    const float* __restrict__ ew3, const float* __restrict__ eb3,
    const float* __restrict__ aw,  const float* __restrict__ ab,
    u16* __restrict__ sB)
{
  __shared__ float in_s[16][32];
  __shared__ float h_a[16][256];
  __shared__ float h_b[16][256];
  const int t = threadIdx.x;
  const int node0 = blockIdx.x * 16;

  for (int idx = t; idx < 16*32; idx += 256) {
    int n = idx >> 5, k = idx & 31;
    int node = node0 + n;
    float v;
    if (k < DXF)      v = x[node*DXF + k];
    else if (k < 31)  v = fs[node*3 + (k - DXF)];
    else              v = fn[node];
    in_s[n][k] = v;
  }
  __syncthreads();

  { // stage 1: 32 -> 256
    float acc[16];
    float bb = eb1[t];
    #pragma unroll
    for (int n=0;n<16;n++) acc[n] = bb;
    for (int k=0;k<32;k++){
      float w = ew1[k*256 + t];
      #pragma unroll
      for (int n=0;n<16;n++) acc[n] = fmaf(in_s[n][k], w, acc[n]);
    }
    #pragma unroll
    for (int n=0;n<16;n++) h_a[n][t] = leakyf(acc[n]);
  }
  __syncthreads();

  if (t < 48){
    int n = t / 3, k = t % 3;
    in_s[n][k] = act[(node0+n)*3 + k];
  }

  { // stage 2: 256 -> 256
    float acc[16];
    float bb = eb2[t];
    #pragma unroll
    for (int n=0;n<16;n++) acc[n] = bb;
    for (int k4=0;k4<256;k4+=4){
      float w0 = ew2[(k4+0)*256 + t];
      float w1 = ew2[(k4+1)*256 + t];
      float w2 = ew2[(k4+2)*256 + t];
      float w3 = ew2[(k4+3)*256 + t];
      #pragma unroll
      for (int n=0;n<16;n++){
        const float4 sv = *reinterpret_cast<const float4*>(&h_a[n][k4]);
        acc[n] = fmaf(sv.x,w0,fmaf(sv.y,w1,fmaf(sv.z,w2,fmaf(sv.w,w3,acc[n]))));
      }
    }
    #pragma unroll
    for (int n=0;n<16;n++) h_b[n][t] = leakyf(acc[n]);
  }
  __syncthreads();

  if (t < 128){ // stage 3: 256 -> 128
    float acc[16];
    float bb = eb3[t];
    #pragma unroll
    for (int n=0;n<16;n++) acc[n] = bb;
    for (int k4=0;k4<256;k4+=4){
      float w0 = ew3[(k4+0)*128 + t];
      float w1 = ew3[(k4+1)*128 + t];
      float w2 = ew3[(k4+2)*128 + t];
      float w3 = ew3[(k4+3)*128 + t];
      #pragma unroll
      for (int n=0;n<16;n++){
        const float4 sv = *reinterpret_cast<const float4*>(&h_b[n][k4]);
        acc[n] = fmaf(sv.x,w0,fmaf(sv.y,w1,fmaf(sv.z,w2,fmaf(sv.w,w3,acc[n]))));
      }
    }
    #pragma unroll
    for (int n=0;n<16;n++) sB[(size_t)(node0+n)*256 + t] = f2bf(leakyf(acc[n]));
  } else { // action linear
    int c = t - 128;
    float w0 = aw[0*128 + c], w1 = aw[1*128 + c], w2 = aw[2*128 + c];
    float bb = ab[c];
    #pragma unroll
    for (int n=0;n<16;n++){
      float v = bb + in_s[n][0]*w0 + in_s[n][1]*w1 + in_s[n][2]*w2;
      sB[(size_t)(node0+n)*256 + 128 + c] = f2bf(v);
    }
  }
}

// ---------------------------------------------------------------------------
// Weight prep: pack conv weights.
// Wpk[l][kb][n][j] bf16, kb=k/8 (k in 0..255), n in 0..1023:
//   n<256: Wf dst | n<512: Ws dst | n<768: Wf src | else Ws src
// wE[l][k][c] = bf16x2(Wf[512+k][c], Ws[512+k][c])
// ---------------------------------------------------------------------------
__global__ __launch_bounds__(256) void prep_kernel(
    const float* __restrict__ cwf, const float* __restrict__ cws,
    u16* __restrict__ Wpk, u32* __restrict__ wE)
{
  int tid = blockIdx.x*256 + threadIdx.x;
  if (tid < 3*32*1024){
    int n  = tid & 1023;
    int kb = (tid >> 10) & 31;
    int l  = tid >> 15;
    const float* wf  = cwf + (size_t)l*538*256;
    const float* wsm = cws + (size_t)l*538*256;
    u16 out[8];
    #pragma unroll
    for (int j=0;j<8;j++){
      int k = kb*8 + j;
      float w;
      if (n < 256)      w = wf [(size_t)k*256 + n];
      else if (n < 512) w = wsm[(size_t)k*256 + (n-256)];
      else if (n < 768) w = wf [(size_t)(256+k)*256 + (n-512)];
      else              w = wsm[(size_t)(256+k)*256 + (n-768)];
      out[j] = f2bf(w);
    }
    *reinterpret_cast<uint4*>(&Wpk[(size_t)tid*8]) = *reinterpret_cast<uint4*>(out);
  } else {
    int t2 = tid - 3*32*1024;
    if (t2 < 3*EDIM*256){
      int c = t2 & 255;
      int k = (t2 >> 8) % EDIM;
      int l = t2 / (EDIM*256);
      const float* wf  = cwf + (size_t)l*538*256;
      const float* wsm = cws + (size_t)l*538*256;
      u32 lo = f2bf(wf [(size_t)(512+k)*256 + c]);
      u32 hi = f2bf(wsm[(size_t)(512+k)*256 + c]);
      wE[t2] = lo | (hi << 16);
    }
  }
}

// ---------------------------------------------------------------------------
// CSR build
// ---------------------------------------------------------------------------
__global__ void hist_kernel(const int* __restrict__ ei, int* __restrict__ cnt){
  int e = blockIdx.x*256 + threadIdx.x;
  if (e < N_EDGES) atomicAdd(&cnt[ei[N_EDGES + e]], 1);
}

__global__ __launch_bounds__(256) void scan1_kernel(
    const int* __restrict__ cnt, int* __restrict__ rowptr, int* __restrict__ partial){
  __shared__ int sd[256];
  int t = threadIdx.x; int idx = blockIdx.x*256 + t;
  int v = (idx < N_NODES) ? cnt[idx] : 0;
  sd[t] = v; __syncthreads();
  for (int off=1; off<256; off<<=1){
    int x2 = (t>=off) ? sd[t-off] : 0;
    __syncthreads();
    sd[t] += x2; __syncthreads();
  }
  if (idx < N_NODES) rowptr[idx] = sd[t] - v;   // block-local exclusive
  if (t == 255) partial[blockIdx.x] = sd[255];
}

__global__ __launch_bounds__(256) void scan2_kernel(int* __restrict__ partial, int nb){
  __shared__ int sd[256];
  int t = threadIdx.x;
  int v = (t<nb) ? partial[t] : 0;
  sd[t] = v; __syncthreads();
  for (int off=1; off<256; off<<=1){
    int x2 = (t>=off) ? sd[t-off] : 0;
    __syncthreads();
    sd[t] += x2; __syncthreads();
  }
  if (t<nb) partial[t] = sd[t] - v;             // exclusive block offsets
}

__global__ __launch_bounds__(256) void scan3_kernel(
    int* __restrict__ rowptr, const int* __restrict__ partial, int* __restrict__ cursor){
  int idx = blockIdx.x*256 + threadIdx.x;
  if (idx < N_NODES){
    int v = rowptr[idx] + partial[blockIdx.x];
    rowptr[idx] = v; cursor[idx] = v;
  }
  if (idx == 0) rowptr[N_NODES] = N_EDGES;
}

// scatter edges into CSR order; precompute truncated gaussian (7 terms, bf16)
__global__ __launch_bounds__(256) void scatter_kernel(
    const int* __restrict__ ei, const float* __restrict__ elen,
    int* __restrict__ cursor, int* __restrict__ srcP, uint4* __restrict__ gaussP)
{
  int e = blockIdx.x*256 + threadIdx.x;
  if (e >= N_EDGES) return;
  int d = ei[N_EDGES + e];
  int pos = atomicAdd(&cursor[d], 1);
  srcP[pos] = ei[e];
  float len = elen[e];
  int k0 = (int)rintf(len*5.f) - 3;
  k0 = min(max(k0,0),19);
  u16 g[8];
  #pragma unroll
  for (int j=0;j<7;j++){
    float dd = len - 0.2f*(float)(k0+j);
    g[j] = f2bf(__expf(-25.f*dd*dd));
  }
  g[7] = (u16)k0;
  gaussP[pos] = *reinterpret_cast<uint4*>(g);
}

// ---------------------------------------------------------------------------
// Proj (MFMA): P[NPAD,1024] bf16 = sB[NPAD,256] @ W'[256,1024]
// block = 4 waves; wave w covers 64 cols; tile 64 rows x 256 cols.
// ---------------------------------------------------------------------------
__global__ __launch_bounds__(256) void proj_kernel(
    const u16* __restrict__ sB, const u16* __restrict__ Wl, u16* __restrict__ P)
{
  const int t = threadIdx.x;
  const int w = t >> 6;
  const int l = t & 63;
  const int q = l >> 4;
  const int r16 = l & 15;
  const int m0 = blockIdx.x * 64;
  const int nb = blockIdx.y * 256 + w * 64;

  f32x4 acc[4][4];
  #pragma unroll
  for (int mi=0;mi<4;mi++)
    #pragma unroll
    for (int ni=0;ni<4;ni++){ acc[mi][ni][0]=0.f; acc[mi][ni][1]=0.f; acc[mi][ni][2]=0.f; acc[mi][ni][3]=0.f; }

  for (int ks=0; ks<8; ks++){
    short8v a[4], b[4];
    #pragma unroll
    for (int mi=0;mi<4;mi++){
      int row = m0 + mi*16 + r16;
      a[mi] = *reinterpret_cast<const short8v*>(&sB[(size_t)row*256 + ks*32 + q*8]);
    }
    #pragma unroll
    for (int ni=0;ni<4;ni++){
      int col = nb + ni*16 + r16;
      b[ni] = *reinterpret_cast<const short8v*>(&Wl[(((size_t)(ks*4+q))*1024 + col)*8]);
    }
    #pragma unroll
    for (int mi=0;mi<4;mi++)
      #pragma unroll
      for (int ni=0;ni<4;ni++)
        acc[mi][ni] = __builtin_amdgcn_mfma_f32_16x16x32_bf16(a[mi], b[ni], acc[mi][ni], 0,0,0);
  }

  #pragma unroll
  for (int mi=0;mi<4;mi++){
    #pragma unroll
    for (int ni=0;ni<4;ni++){
      int col = nb + ni*16 + r16;
      #pragma unroll
      for (int r=0;r<4;r++){
        int row = m0 + mi*16 + q*4 + r;
        P[(size_t)row*1024 + col] = f2bf(acc[mi][ni][r]);
      }
    }
  }
}

// ---------------------------------------------------------------------------
// CSR edge aggregation: per node, sum sigmoid(gate)*softplus(core) over in-edges,
// residual + optional leaky, in-place bf16 update of sB.
// ---------------------------------------------------------------------------
__global__ __launch_bounds__(256) void csr_edge_kernel(
    const u16* __restrict__ P, u16* __restrict__ sB,
    const u32* __restrict__ wEl,
    const float* __restrict__ bfv, const float* __restrict__ bsv,
    const int* __restrict__ rowptr, const int* __restrict__ srcP,
    const uint4* __restrict__ gaussP, int do_leaky)
{
  __shared__ u32 wS[EDIM*256];
  const int t = threadIdx.x;
  for (int i=t; i<EDIM*256; i+=256) wS[i] = wEl[i];
  const float bf_t = bfv[t], bs_t = bsv[t];
  __syncthreads();

  for (int node = blockIdx.x; node < N_NODES; node += gridDim.x){
    const int r0 = rowptr[node], r1 = rowptr[node+1];
    const float Pg0 = bf_t + bf2f(P[(size_t)node*1024 + t]);
    const float Pc0 = bs_t + bf2f(P[(size_t)node*1024 + 256 + t]);
    float accS = 0.f;
    for (int i=r0; i<r1; i++){
      int sn = srcP[i];
      uint4 gq = gaussP[i];
      const u16* ps = &P[(size_t)sn*1024 + 512];
      float gf = Pg0 + bf2f(ps[t]);
      float gs = Pc0 + bf2f(ps[256+t]);
      u16 gu[8]; *reinterpret_cast<uint4*>(gu) = gq;
      const int k0 = gu[7];
      const u32* wrow = &wS[k0*256 + t];
      #pragma unroll
      for (int j=0;j<7;j++){
        float g = bf2f(gu[j]);
        u32 wv = wrow[j*256];
        gf = fmaf(g, __builtin_bit_cast(float, wv << 16), gf);
        gs = fmaf(g, __builtin_bit_cast(float, wv & 0xffff0000u), gs);
      }
      float gate = 1.f/(1.f + __expf(-gf));
      float u = __expf(-fabsf(gs));
      float sp = fmaxf(gs, 0.f) + __logf(1.f + u);
      accS += gate * sp;
    }
    float v = bf2f(sB[(size_t)node*256 + t]) + accS;
    if (do_leaky) v = leakyf(v);
    sB[(size_t)node*256 + t] = f2bf(v);
  }
}

// ---------------------------------------------------------------------------
// Pool + head
// ---------------------------------------------------------------------------
__global__ __launch_bounds__(256) void pool_kernel(
    const u16* __restrict__ sB, const int* __restrict__ batch, float* __restrict__ y)
{
  const int t = threadIdx.x;
  int n0 = blockIdx.x * 64;
  int nend = min(n0 + 64, N_NODES);
  float acc = 0.f; int cur = -1;
  for (int n=n0; n<nend; n++){
    int g = batch[n];
    if (g != cur){
      if (cur >= 0) atomicAdd(&y[cur*256 + t], acc);
      acc = 0.f; cur = g;
    }
    acc += bf2f(sB[(size_t)n*256 + t]);
  }
  if (cur >= 0) atomicAdd(&y[cur*256 + t], acc);
}

__global__ __launch_bounds__(256) void desc_kernel(
    const float* __restrict__ y,
    const float* __restrict__ w1, const float* __restrict__ b1,
    const float* __restrict__ w2, const float* __restrict__ b2,
    float* __restrict__ out)
{
  __shared__ float yS[256];
  __shared__ float red[256];
  const int g = blockIdx.x, t = threadIdx.x;
  yS[t] = y[g*256 + t];
  __syncthreads();
  float acc = b1[t];
  for (int k4=0;k4<256;k4+=4){
    float4 v = *reinterpret_cast<const float4*>(&yS[k4]);
    acc += v.x*w1[(k4+0)*256+t] + v.y*w1[(k4+1)*256+t]
         + v.z*w1[(k4+2)*256+t] + v.w*w1[(k4+3)*256+t];
  }
  red[t] = fmaxf(acc, 0.f) * w2[t];
  __syncthreads();
  for (int off=128; off>0; off>>=1){
    if (t < off) red[t] += red[t+off];
    __syncthreads();
  }
  if (t == 0) out[g] = red[0] + b2[0];
}

// ---------------------------------------------------------------------------
extern "C" void kernel_launch(void* const* d_in, const int* in_sizes, int n_in,
                              void* d_out, int out_size, void* d_ws, size_t ws_size,
                              hipStream_t stream)
{
  const float* x    = (const float*)d_in[0];
  const float* fs   = (const float*)d_in[1];
  const float* fn   = (const float*)d_in[2];
  const float* act  = (const float*)d_in[3];
  const float* elen = (const float*)d_in[4];
  const float* ew1  = (const float*)d_in[5];
  const float* eb1  = (const float*)d_in[6];
  const float* ew2  = (const float*)d_in[7];
  const float* eb2  = (const float*)d_in[8];
  const float* ew3  = (const float*)d_in[9];
  const float* eb3  = (const float*)d_in[10];
  const float* aw   = (const float*)d_in[11];
  const float* ab   = (const float*)d_in[12];
  const float* cwf  = (const float*)d_in[13];
  const float* cbf  = (const float*)d_in[14];
  const float* cws  = (const float*)d_in[15];
  const float* cbs  = (const float*)d_in[16];
  const float* dw1  = (const float*)d_in[17];
  const float* db1  = (const float*)d_in[18];
  const float* dw2  = (const float*)d_in[19];
  const float* db2  = (const float*)d_in[20];
  const int*   ei   = (const int*)d_in[21];
  const int*   batch= (const int*)d_in[22];
  float* out = (float*)d_out;

  char* ws = (char*)d_ws;
  size_t off = 0;
  auto carve = [&](size_t bytes)->char*{
    char* p = ws + off; off += (bytes + 255) & ~(size_t)255; return p;
  };
  u16*  sB     = (u16*) carve((size_t)NPAD*256*2);
  u16*  P      = (u16*) carve((size_t)NPAD*1024*2);
  u16*  Wpk    = (u16*) carve((size_t)3*32*1024*8*2);
  u32*  wE     = (u32*) carve((size_t)3*EDIM*256*4);
  int*  rowptr = (int*) carve((size_t)(N_NODES+1)*4);
  int*  cursor = (int*) carve((size_t)N_NODES*4);
  int*  cnt    = (int*) carve((size_t)N_NODES*4);
  int*  partial= (int*) carve(256*4);
  int*  srcP   = (int*) carve((size_t)N_EDGES*4);
  uint4* gaussP= (uint4*)carve((size_t)N_EDGES*16);
  float* y     = (float*)carve((size_t)G_GRAPHS*256*4);
  if (off > ws_size) return;

  hipMemsetAsync(cnt, 0, (size_t)N_NODES*4, stream);
  hipMemsetAsync(y, 0, (size_t)G_GRAPHS*256*4, stream);

  prep_kernel<<<462, 256, 0, stream>>>(cwf, cws, Wpk, wE);
  embed_kernel<<<N_NODES/16, 256, 0, stream>>>(x, fs, fn, act,
      ew1, eb1, ew2, eb2, ew3, eb3, aw, ab, sB);

  const int EB = (N_EDGES + 255)/256;          // 3125
  const int SB = (N_NODES + 255)/256;          // 196
  hist_kernel<<<EB, 256, 0, stream>>>(ei, cnt);
  scan1_kernel<<<SB, 256, 0, stream>>>(cnt, rowptr, partial);
  scan2_kernel<<<1, 256, 0, stream>>>(partial, SB);
  scan3_kernel<<<SB, 256, 0, stream>>>(rowptr, partial, cursor);
  scatter_kernel<<<EB, 256, 0, stream>>>(ei, elen, cursor, srcP, gaussP);

  for (int l=0; l<3; l++){
    proj_kernel<<<dim3(NPAD/64, 4), 256, 0, stream>>>(
        sB, Wpk + (size_t)l*32*1024*8, P);
    csr_edge_kernel<<<2048, 256, 0, stream>>>(
        P, sB, wE + (size_t)l*EDIM*256, cbf + l*256, cbs + l*256,
        rowptr, srcP, gaussP, (l<2) ? 1 : 0);
  }

  pool_kernel<<<(N_NODES+63)/64, 256, 0, stream>>>(sB, batch, y);
  desc_kernel<<<G_GRAPHS, 256, 0, stream>>>(y, dw1, db1, dw2, db2, out);
}

// Round 3
// 1107.413 us; speedup vs baseline: 5.4174x; 1.7044x over previous
//
#include <hip/hip_runtime.h>
#include <hip/hip_bf16.h>

#define N_NODES 50000
#define NPAD    50048
#define N_EDGES 800000
#define EDIM 26
#define DXF 28
#define G_GRAPHS 64
#define NQ 2048

typedef __attribute__((ext_vector_type(8))) short short8v;
typedef __attribute__((ext_vector_type(4))) float f32x4;
typedef unsigned short u16;
typedef unsigned int u32;

__device__ __forceinline__ float leakyf(float x){ return x >= 0.f ? x : 0.01f*x; }
__device__ __forceinline__ u16 f2bf(float f){
  __hip_bfloat16 h = __float2bfloat16(f);
  return __builtin_bit_cast(u16, h);
}
__device__ __forceinline__ float bf2f(u16 u){
  return __builtin_bit_cast(float, (u32)u << 16);
}
__device__ __forceinline__ u32 packbf(float a, float b){
  return (u32)f2bf(a) | ((u32)f2bf(b) << 16);
}
__device__ __forceinline__ float lo16(u32 v){ return __builtin_bit_cast(float, v << 16); }
__device__ __forceinline__ float hi16(u32 v){ return __builtin_bit_cast(float, v & 0xffff0000u); }

// ---------------------------------------------------------------------------
// prep: pack all weights to bf16 MFMA fragment layouts.
// Wpk2 (conv): packed col nn in [0,1024): side=nn>>9 (0=dst rows 0..255 of W,
//   1=src rows 256..511), g=(nn>>4)&31, r=nn&15, type=g&1 (0=Wf,1=Ws),
//   ch=(g>>1)*16+r.  Wpk2[l][kb][nn][j] = W[side*256+kb*8+j][ch], j=0..7.
// w1pk/w2pk/w3pk: embed MLP weights, [kb][col][8] with k=kb*8+j.
// ---------------------------------------------------------------------------
__global__ __launch_bounds__(256) void prep_kernel(
    const float* __restrict__ cwf, const float* __restrict__ cws,
    const float* __restrict__ ew1, const float* __restrict__ ew2,
    const float* __restrict__ ew3,
    u16* __restrict__ Wpk, u16* __restrict__ w1pk,
    u16* __restrict__ w2pk, u16* __restrict__ w3pk)
{
  int tid = blockIdx.x*256 + threadIdx.x;
  u16 out[8];
  if (tid < 98304){
    int nn  = tid & 1023;
    int kb  = (tid >> 10) & 31;
    int lyr = tid >> 15;
    int side = nn >> 9, g = (nn >> 4) & 31, r = nn & 15;
    int type = g & 1, ch = (g >> 1)*16 + r;
    const float* W = (type ? cws : cwf) + (size_t)lyr*538*256;
    #pragma unroll
    for (int j=0;j<8;j++)
      out[j] = f2bf(W[(size_t)(side*256 + kb*8 + j)*256 + ch]);
    *reinterpret_cast<uint4*>(&Wpk[(size_t)tid*8]) = *reinterpret_cast<uint4*>(out);
  } else if (tid < 99328){
    int i = tid - 98304;  int kq = i >> 8, col = i & 255;
    #pragma unroll
    for (int j=0;j<8;j++) out[j] = f2bf(ew1[(kq*8+j)*256 + col]);
    *reinterpret_cast<uint4*>(&w1pk[(size_t)i*8]) = *reinterpret_cast<uint4*>(out);
  } else if (tid < 107520){
    int i = tid - 99328;  int kb = i >> 8, col = i & 255;
    #pragma unroll
    for (int j=0;j<8;j++) out[j] = f2bf(ew2[(kb*8+j)*256 + col]);
    *reinterpret_cast<uint4*>(&w2pk[(size_t)i*8]) = *reinterpret_cast<uint4*>(out);
  } else if (tid < 111616){
    int i = tid - 107520; int kb = i >> 7, col = i & 127;
    #pragma unroll
    for (int j=0;j<8;j++) out[j] = f2bf(ew3[(kb*8+j)*128 + col]);
    *reinterpret_cast<uint4*>(&w3pk[(size_t)i*8]) = *reinterpret_cast<uint4*>(out);
  }
}

// ---------------------------------------------------------------------------
// tfs: quantized edge-logit table. TFS[l][q][c] = pack(bf + gauss(len_q)@Wf_e,
// bs + gauss@Ws_e). len_q = q*5/NQ, full 26-term sum, bias folded in.
// ---------------------------------------------------------------------------
__global__ __launch_bounds__(256) void tfs_kernel(
    const float* __restrict__ cwf, const float* __restrict__ cws,
    const float* __restrict__ cbf, const float* __restrict__ cbs,
    u32* __restrict__ TFS)
{
  int q = blockIdx.x & (NQ-1);
  int lyr = blockIdx.x >> 11;
  int c = threadIdx.x;
  const float* wf = cwf + (size_t)lyr*538*256 + (size_t)512*256;
  const float* ws = cws + (size_t)lyr*538*256 + (size_t)512*256;
  float f = cbf[lyr*256 + c], s = cbs[lyr*256 + c];
  float len = (float)q * (5.f/NQ);
  for (int k=0;k<EDIM;k++){
    float d = len - 0.2f*(float)k;
    float g = __expf(-25.f*d*d);
    f += g * wf[k*256 + c];
    s += g * ws[k*256 + c];
  }
  TFS[((size_t)lyr*NQ + q)*256 + c] = packbf(f, s);
}

// ---------------------------------------------------------------------------
// Embed (MFMA): 32 nodes per block.
// stage1 [32,32]@[32,256] -> h1; stage2 [32,256]@[256,256] -> h2;
// stage3 [32,256]@[256,128] -> sB[:,0:128]; action -> sB[:,128:256].
// h1/h2 XOR-swizzled ((row&7)<<3 on u16 index) for conflict-free b128 reads.
// ---------------------------------------------------------------------------
__global__ __launch_bounds__(256) void embed_kernel(
    const float* __restrict__ x, const float* __restrict__ fs,
    const float* __restrict__ fn, const float* __restrict__ act,
    const u16* __restrict__ w1pk, const float* __restrict__ eb1,
    const u16* __restrict__ w2pk, const float* __restrict__ eb2,
    const u16* __restrict__ w3pk, const float* __restrict__ eb3,
    const float* __restrict__ aw,  const float* __restrict__ ab,
    u16* __restrict__ sB)
{
  __shared__ u16 inA[32*32];
  __shared__ float actS[32*4];
  __shared__ u16 h1[32*256];
  __shared__ u16 h2[32*256];
  const int t = threadIdx.x;
  const int w = t >> 6, l = t & 63, q = l >> 4, r16 = l & 15;
  const int node0 = blockIdx.x * 32;

  for (int idx=t; idx<1024; idx+=256){
    int n = idx >> 5, k = idx & 31;
    int node = node0 + n;
    float v = 0.f;
    if (node < N_NODES){
      if (k < DXF)      v = x[node*DXF + k];
      else if (k < 31)  v = fs[node*3 + (k - DXF)];
      else              v = fn[node];
    }
    inA[idx] = f2bf(v);
  }
  { int n = t >> 2, k = t & 3;
    float v = 0.f;
    if (n < 32 && k < 3 && node0 + n < N_NODES) v = act[(node0+n)*3 + k];
    if (n < 32) actS[t] = v; }
  __syncthreads();

  f32x4 acc[2][4];
  // ---- stage 1 ----
  #pragma unroll
  for (int mi=0;mi<2;mi++)
    #pragma unroll
    for (int ni=0;ni<4;ni++){ acc[mi][ni][0]=0;acc[mi][ni][1]=0;acc[mi][ni][2]=0;acc[mi][ni][3]=0; }
  {
    short8v a[2], b[4];
    #pragma unroll
    for (int mi=0;mi<2;mi++)
      a[mi] = *reinterpret_cast<const short8v*>(&inA[(mi*16+r16)*32 + q*8]);
    #pragma unroll
    for (int ni=0;ni<4;ni++)
      b[ni] = *reinterpret_cast<const short8v*>(&w1pk[((size_t)q*256 + w*64 + ni*16 + r16)*8]);
    #pragma unroll
    for (int mi=0;mi<2;mi++)
      #pragma unroll
      for (int ni=0;ni<4;ni++)
        acc[mi][ni] = __builtin_amdgcn_mfma_f32_16x16x32_bf16(a[mi], b[ni], acc[mi][ni], 0,0,0);
  }
  #pragma unroll
  for (int ni=0;ni<4;ni++){
    int col = w*64 + ni*16 + r16;
    float bias = eb1[col];
    #pragma unroll
    for (int mi=0;mi<2;mi++)
      #pragma unroll
      for (int r=0;r<4;r++){
        int row = mi*16 + q*4 + r;
        h1[(row*256 + col) ^ ((row&7)<<3)] = f2bf(leakyf(acc[mi][ni][r] + bias));
      }
  }
  __syncthreads();

  // ---- stage 2 ----
  #pragma unroll
  for (int mi=0;mi<2;mi++)
    #pragma unroll
    for (int ni=0;ni<4;ni++){ acc[mi][ni][0]=0;acc[mi][ni][1]=0;acc[mi][ni][2]=0;acc[mi][ni][3]=0; }
  for (int ks=0;ks<8;ks++){
    short8v a[2], b[4];
    #pragma unroll
    for (int mi=0;mi<2;mi++){
      int row = mi*16 + r16;
      a[mi] = *reinterpret_cast<const short8v*>(&h1[(row*256 + ks*32 + q*8) ^ ((row&7)<<3)]);
    }
    #pragma unroll
    for (int ni=0;ni<4;ni++)
      b[ni] = *reinterpret_cast<const short8v*>(&w2pk[((size_t)(ks*4+q)*256 + w*64 + ni*16 + r16)*8]);
    #pragma unroll
    for (int mi=0;mi<2;mi++)
      #pragma unroll
      for (int ni=0;ni<4;ni++)
        acc[mi][ni] = __builtin_amdgcn_mfma_f32_16x16x32_bf16(a[mi], b[ni], acc[mi][ni], 0,0,0);
  }
  #pragma unroll
  for (int ni=0;ni<4;ni++){
    int col = w*64 + ni*16 + r16;
    float bias = eb2[col];
    #pragma unroll
    for (int mi=0;mi<2;mi++)
      #pragma unroll
      for (int r=0;r<4;r++){
        int row = mi*16 + q*4 + r;
        h2[(row*256 + col) ^ ((row&7)<<3)] = f2bf(leakyf(acc[mi][ni][r] + bias));
      }
  }
  __syncthreads();

  // ---- stage 3 (waves 0,1) + action (waves 2,3) ----
  if (w < 2){
    #pragma unroll
    for (int mi=0;mi<2;mi++)
      #pragma unroll
      for (int ni=0;ni<4;ni++){ acc[mi][ni][0]=0;acc[mi][ni][1]=0;acc[mi][ni][2]=0;acc[mi][ni][3]=0; }
    for (int ks=0;ks<8;ks++){
      short8v a[2], b[4];
      #pragma unroll
      for (int mi=0;mi<2;mi++){
        int row = mi*16 + r16;
        a[mi] = *reinterpret_cast<const short8v*>(&h2[(row*256 + ks*32 + q*8) ^ ((row&7)<<3)]);
      }
      #pragma unroll
      for (int ni=0;ni<4;ni++)
        b[ni] = *reinterpret_cast<const short8v*>(&w3pk[((size_t)(ks*4+q)*128 + w*64 + ni*16 + r16)*8]);
      #pragma unroll
      for (int mi=0;mi<2;mi++)
        #pragma unroll
        for (int ni=0;ni<4;ni++)
          acc[mi][ni] = __builtin_amdgcn_mfma_f32_16x16x32_bf16(a[mi], b[ni], acc[mi][ni], 0,0,0);
    }
    #pragma unroll
    for (int ni=0;ni<4;ni++){
      int col = w*64 + ni*16 + r16;
      float bias = eb3[col];
      #pragma unroll
      for (int mi=0;mi<2;mi++)
        #pragma unroll
        for (int r=0;r<4;r++){
          int row = mi*16 + q*4 + r;
          sB[(size_t)(node0+row)*256 + col] = f2bf(leakyf(acc[mi][ni][r] + bias));
        }
    }
  } else {
    int c = t - 128;   // 0..127
    float w0 = aw[c], w1 = aw[128+c], w2 = aw[256+c], bb = ab[c];
    for (int n=0;n<32;n++){
      float v = bb + actS[n*4]*w0 + actS[n*4+1]*w1 + actS[n*4+2]*w2;
      sB[(size_t)(node0+n)*256 + 128 + c] = f2bf(v);
    }
  }
}

// ---------------------------------------------------------------------------
// CSR build
// ---------------------------------------------------------------------------
__global__ void hist_kernel(const int* __restrict__ ei, int* __restrict__ cnt){
  int e = blockIdx.x*256 + threadIdx.x;
  if (e < N_EDGES) atomicAdd(&cnt[ei[N_EDGES + e]], 1);
}

__global__ __launch_bounds__(256) void scan1_kernel(
    const int* __restrict__ cnt, int* __restrict__ rowptr, int* __restrict__ partial){
  __shared__ int sd[256];
  int t = threadIdx.x; int idx = blockIdx.x*256 + t;
  int v = (idx < N_NODES) ? cnt[idx] : 0;
  sd[t] = v; __syncthreads();
  for (int off=1; off<256; off<<=1){
    int x2 = (t>=off) ? sd[t-off] : 0;
    __syncthreads();
    sd[t] += x2; __syncthreads();
  }
  if (idx < N_NODES) rowptr[idx] = sd[t] - v;
  if (t == 255) partial[blockIdx.x] = sd[255];
}

__global__ __launch_bounds__(256) void scan2_kernel(int* __restrict__ partial, int nb){
  __shared__ int sd[256];
  int t = threadIdx.x;
  int v = (t<nb) ? partial[t] : 0;
  sd[t] = v; __syncthreads();
  for (int off=1; off<256; off<<=1){
    int x2 = (t>=off) ? sd[t-off] : 0;
    __syncthreads();
    sd[t] += x2; __syncthreads();
  }
  if (t<nb) partial[t] = sd[t] - v;
}

__global__ __launch_bounds__(256) void scan3_kernel(
    int* __restrict__ rowptr, const int* __restrict__ partial, int* __restrict__ cursor){
  int idx = blockIdx.x*256 + threadIdx.x;
  if (idx < N_NODES){
    int v = rowptr[idx] + partial[blockIdx.x];
    rowptr[idx] = v; cursor[idx] = v;
  }
  if (idx == 0) rowptr[N_NODES] = N_EDGES;
}

// scatter: CSR order; rec = src(16b) | q(quantized len)<<16
__global__ __launch_bounds__(256) void scatter_kernel(
    const int* __restrict__ ei, const float* __restrict__ elen,
    int* __restrict__ cursor, u32* __restrict__ recP)
{
  int e = blockIdx.x*256 + threadIdx.x;
  if (e >= N_EDGES) return;
  int d = ei[N_EDGES + e];
  int pos = atomicAdd(&cursor[d], 1);
  int qq = (int)rintf(elen[e] * ((float)NQ/5.f));
  qq = min(max(qq,0), NQ-1);
  recP[pos] = (u32)ei[e] | ((u32)qq << 16);
}

// ---------------------------------------------------------------------------
// Proj (MFMA): Pdst/Psrc[n][c] = packed bf16 (gate_logit_part, core_logit_part).
// grid (NPAD/64, 2): y=0 dst side, y=1 src side. Wave covers 128 packed cols
// (ni=0..7, f/s interleaved at 16-col granularity -> same lane holds both).
// ---------------------------------------------------------------------------
__global__ __launch_bounds__(256) void proj_kernel(
    const u16* __restrict__ sB, const u16* __restrict__ Wl,
    u32* __restrict__ Pdst, u32* __restrict__ Psrc)
{
  const int t = threadIdx.x;
  const int w = t >> 6, l = t & 63, q = l >> 4, r16 = l & 15;
  const int m0 = blockIdx.x * 64;
  const int y  = blockIdx.y;

  f32x4 acc[4][8];
  #pragma unroll
  for (int mi=0;mi<4;mi++)
    #pragma unroll
    for (int ni=0;ni<8;ni++){ acc[mi][ni][0]=0;acc[mi][ni][1]=0;acc[mi][ni][2]=0;acc[mi][ni][3]=0; }

  for (int ks=0; ks<8; ks++){
    short8v a[4], b[8];
    #pragma unroll
    for (int mi=0;mi<4;mi++)
      a[mi] = *reinterpret_cast<const short8v*>(&sB[(size_t)(m0+mi*16+r16)*256 + ks*32 + q*8]);
    #pragma unroll
    for (int ni=0;ni<8;ni++)
      b[ni] = *reinterpret_cast<const short8v*>(&Wl[((size_t)(ks*4+q)*1024 + y*512 + w*128 + ni*16 + r16)*8]);
    #pragma unroll
    for (int mi=0;mi<4;mi++)
      #pragma unroll
      for (int ni=0;ni<8;ni++)
        acc[mi][ni] = __builtin_amdgcn_mfma_f32_16x16x32_bf16(a[mi], b[ni], acc[mi][ni], 0,0,0);
  }

  u32* outP = (y == 0) ? Pdst : Psrc;
  #pragma unroll
  for (int mi=0;mi<4;mi++){
    #pragma unroll
    for (int p=0;p<4;p++){
      int ch = w*64 + p*16 + r16;
      #pragma unroll
      for (int r=0;r<4;r++){
        int row = m0 + mi*16 + q*4 + r;
        outP[(size_t)row*256 + ch] = packbf(acc[mi][2*p][r], acc[mi][2*p+1][r]);
      }
    }
  }
}

// ---------------------------------------------------------------------------
// CSR edge aggregation: one block per node, thread = channel.
// gf = Pdst.f + Psrc.f + TFS.f ; gs likewise. No LDS.
// ---------------------------------------------------------------------------
__global__ __launch_bounds__(256) void csr_edge_kernel(
    const u32* __restrict__ Pdst, const u32* __restrict__ Psrc,
    u16* __restrict__ sB, const u32* __restrict__ TFSl,
    const int* __restrict__ rowptr, const u32* __restrict__ recP,
    int do_leaky)
{
  const int t = threadIdx.x;
  const int node = blockIdx.x;
  const int r0 = rowptr[node], r1 = rowptr[node+1];
  u32 pd = Pdst[(size_t)node*256 + t];
  const float Pg0 = lo16(pd), Pc0 = hi16(pd);
  float accS = 0.f;
  for (int i=r0; i<r1; i++){
    u32 rec = recP[i];
    u32 pv = Psrc[(size_t)(rec & 0xffffu)*256 + t];
    u32 tv = TFSl[(size_t)(rec >> 16)*256 + t];
    float gf = Pg0 + lo16(pv) + lo16(tv);
    float gs = Pc0 + hi16(pv) + hi16(tv);
    float gate = 1.f/(1.f + __expf(-gf));
    float u = __expf(-fabsf(gs));
    float sp = fmaxf(gs, 0.f) + __logf(1.f + u);
    accS += gate * sp;
  }
  float v = bf2f(sB[(size_t)node*256 + t]) + accS;
  if (do_leaky) v = leakyf(v);
  sB[(size_t)node*256 + t] = f2bf(v);
}

// ---------------------------------------------------------------------------
// Pool + head
// ---------------------------------------------------------------------------
__global__ __launch_bounds__(256) void pool_kernel(
    const u16* __restrict__ sB, const int* __restrict__ batch, float* __restrict__ y)
{
  const int t = threadIdx.x;
  int n0 = blockIdx.x * 64;
  int nend = min(n0 + 64, N_NODES);
  float acc = 0.f; int cur = -1;
  for (int n=n0; n<nend; n++){
    int g = batch[n];
    if (g != cur){
      if (cur >= 0) atomicAdd(&y[cur*256 + t], acc);
      acc = 0.f; cur = g;
    }
    acc += bf2f(sB[(size_t)n*256 + t]);
  }
  if (cur >= 0) atomicAdd(&y[cur*256 + t], acc);
}

__global__ __launch_bounds__(256) void desc_kernel(
    const float* __restrict__ y,
    const float* __restrict__ w1, const float* __restrict__ b1,
    const float* __restrict__ w2, const float* __restrict__ b2,
    float* __restrict__ out)
{
  __shared__ float yS[256];
  __shared__ float red[256];
  const int g = blockIdx.x, t = threadIdx.x;
  yS[t] = y[g*256 + t];
  __syncthreads();
  float acc = b1[t];
  for (int k4=0;k4<256;k4+=4){
    float4 v = *reinterpret_cast<const float4*>(&yS[k4]);
    acc += v.x*w1[(k4+0)*256+t] + v.y*w1[(k4+1)*256+t]
         + v.z*w1[(k4+2)*256+t] + v.w*w1[(k4+3)*256+t];
  }
  red[t] = fmaxf(acc, 0.f) * w2[t];
  __syncthreads();
  for (int off=128; off>0; off>>=1){
    if (t < off) red[t] += red[t+off];
    __syncthreads();
  }
  if (t == 0) out[g] = red[0] + b2[0];
}

// ---------------------------------------------------------------------------
extern "C" void kernel_launch(void* const* d_in, const int* in_sizes, int n_in,
                              void* d_out, int out_size, void* d_ws, size_t ws_size,
                              hipStream_t stream)
{
  const float* x    = (const float*)d_in[0];
  const float* fs   = (const float*)d_in[1];
  const float* fn   = (const float*)d_in[2];
  const float* act  = (const float*)d_in[3];
  const float* elen = (const float*)d_in[4];
  const float* ew1  = (const float*)d_in[5];
  const float* eb1  = (const float*)d_in[6];
  const float* ew2  = (const float*)d_in[7];
  const float* eb2  = (const float*)d_in[8];
  const float* ew3  = (const float*)d_in[9];
  const float* eb3  = (const float*)d_in[10];
  const float* aw   = (const float*)d_in[11];
  const float* ab   = (const float*)d_in[12];
  const float* cwf  = (const float*)d_in[13];
  const float* cbf  = (const float*)d_in[14];
  const float* cws  = (const float*)d_in[15];
  const float* cbs  = (const float*)d_in[16];
  const float* dw1  = (const float*)d_in[17];
  const float* db1  = (const float*)d_in[18];
  const float* dw2  = (const float*)d_in[19];
  const float* db2  = (const float*)d_in[20];
  const int*   ei   = (const int*)d_in[21];
  const int*   batch= (const int*)d_in[22];
  float* out = (float*)d_out;

  char* ws = (char*)d_ws;
  size_t off = 0;
  auto carve = [&](size_t bytes)->char*{
    char* p = ws + off; off += (bytes + 255) & ~(size_t)255; return p;
  };
  u16*  sB     = (u16*) carve((size_t)NPAD*256*2);
  u32*  Pdst   = (u32*) carve((size_t)NPAD*256*4);
  u32*  Psrc   = (u32*) carve((size_t)NPAD*256*4);
  u16*  Wpk    = (u16*) carve((size_t)3*32*1024*8*2);
  u16*  w1pk   = (u16*) carve((size_t)1024*8*2);
  u16*  w2pk   = (u16*) carve((size_t)8192*8*2);
  u16*  w3pk   = (u16*) carve((size_t)4096*8*2);
  u32*  TFS    = (u32*) carve((size_t)3*NQ*256*4);
  int*  rowptr = (int*) carve((size_t)(N_NODES+1)*4);
  int*  cursor = (int*) carve((size_t)N_NODES*4);
  int*  cnt    = (int*) carve((size_t)N_NODES*4);
  int*  partial= (int*) carve(256*4);
  u32*  recP   = (u32*) carve((size_t)N_EDGES*4);
  float* y     = (float*)carve((size_t)G_GRAPHS*256*4);
  if (off > ws_size) return;

  hipMemsetAsync(cnt, 0, (size_t)N_NODES*4, stream);
  hipMemsetAsync(y, 0, (size_t)G_GRAPHS*256*4, stream);

  prep_kernel<<<436, 256, 0, stream>>>(cwf, cws, ew1, ew2, ew3,
                                       Wpk, w1pk, w2pk, w3pk);
  tfs_kernel<<<3*NQ, 256, 0, stream>>>(cwf, cws, cbf, cbs, TFS);
  embed_kernel<<<NPAD/32, 256, 0, stream>>>(x, fs, fn, act,
      w1pk, eb1, w2pk, eb2, w3pk, eb3, aw, ab, sB);

  const int EB = (N_EDGES + 255)/256;          // 3125
  const int SB = (N_NODES + 255)/256;          // 196
  hist_kernel<<<EB, 256, 0, stream>>>(ei, cnt);
  scan1_kernel<<<SB, 256, 0, stream>>>(cnt, rowptr, partial);
  scan2_kernel<<<1, 256, 0, stream>>>(partial, SB);
  scan3_kernel<<<SB, 256, 0, stream>>>(rowptr, partial, cursor);
  scatter_kernel<<<EB, 256, 0, stream>>>(ei, elen, cursor, recP);

  for (int l=0; l<3; l++){
    proj_kernel<<<dim3(NPAD/64, 2), 256, 0, stream>>>(
        sB, Wpk + (size_t)l*32*1024*8, Pdst, Psrc);
    csr_edge_kernel<<<N_NODES, 256, 0, stream>>>(
        Pdst, Psrc, sB, TFS + (size_t)l*NQ*256, rowptr, recP, (l<2) ? 1 : 0);
  }

  pool_kernel<<<(N_NODES+63)/64, 256, 0, stream>>>(sB, batch, y);
  desc_kernel<<<G_GRAPHS, 256, 0, stream>>>(y, dw1, db1, dw2, db2, out);
}